// Round 8
// baseline (153.013 us; speedup 1.0000x reference)
//
#include <hip/hip_runtime.h>
#include <hip/hip_bf16.h>

typedef __hip_bfloat16 bf16;
typedef short bf16x8 __attribute__((ext_vector_type(8)));
typedef float f32x4 __attribute__((ext_vector_type(4)));

#define S_LEN 4096
#define NBATCH 2
#define EDIM 1024
#define DDIM 64
#define MROWS (NBATCH * S_LEN)   // 8192

#define GLOBAL_AS __attribute__((address_space(1)))
#define LDS_AS __attribute__((address_space(3)))

union frag_u { bf16x8 v; bf16 e[8]; };

// async 16B global -> LDS (dest wave-uniform; HW adds lane*16; src per-lane)
__device__ __forceinline__ void async_ld16(const void* gp, void* lp) {
  __builtin_amdgcn_global_load_lds((const GLOBAL_AS void*)gp,
                                   (LDS_AS void*)lp, 16, 0, 0);
}

// f32x8 -> split bf16 hi/lo fragments (x ~= hi + lo, rel err ~2^-17)
__device__ __forceinline__ void cvt_split(const float4& a, const float4& b,
                                          bf16x8& hi, bf16x8& lo) {
  float v[8] = {a.x, a.y, a.z, a.w, b.x, b.y, b.z, b.w};
  frag_u h, l;
#pragma unroll
  for (int e = 0; e < 8; e++) {
    bf16 hh = __float2bfloat16(v[e]);
    h.e[e] = hh;
    l.e[e] = __float2bfloat16(v[e] - __bfloat162float(hh));
  }
  hi = h.v;
  lo = l.v;
}

// ---------------------------------------------------------------------------
// PREP kernel v13 — pack + Vsum partials + flag zero, grid 304 x 256.
// Blocks 0-47: pack W (f32 k-major) -> split-bf16 round-major Wt2 (layout
//   identical to v5..v12; see comments in pack path). Block 0 zeroes flags.
// Blocks 48-303 (v = bid-48, 256 blocks): Vsum partials WITHOUT atomics:
//   rowsum of x rows [32v, 32v+32) (coalesced full-row float4 sweeps; also
//   L3-WARMS x for the main kernel's A staging), then
//   Vpart[v][col] = sum_k rowsum[k] * Wv[k][col]  (exclusive slot).
//   Main kernel sums the 128 partials per batch + S*bv -> Vsum.
//   (Vsum = colsum(x) @ Wv + S*bv algebraically == column sums of V.)
// ---------------------------------------------------------------------------
__global__ __launch_bounds__(256) void prep_kernel(
    const float* __restrict__ x, const float* __restrict__ Wq,
    const float* __restrict__ Wk, const float* __restrict__ Wv,
    bf16* __restrict__ Wt2_hi, bf16* __restrict__ Wt2_lo,
    float* __restrict__ Vpart, int* __restrict__ flags) {
  __shared__ float smem[64 * 65];             // pack tile / vsum scratch
  const int t = threadIdx.x;
  const int bid = blockIdx.x;

  if (bid < 48) {                             // ---- pack path ----
    if (bid == 0) flags[t] = 0;               // 256 flags zeroed
    const int mat = bid >> 4;
    const int kb = bid & 15;                  // 64-k block -> rounds 2kb,2kb+1
    const float* W = (mat == 0) ? Wq : ((mat == 1) ? Wk : Wv);
#pragma unroll
    for (int i = 0; i < 4; i++) {
      int F = (i * 256 + t) * 4;              // flat f32 idx in [0,4096)
      int k = F >> 6;
      int n4 = F & 63;
      float4 v =
          *(const float4*)(const void*)(W + (size_t)(kb * 64 + k) * 64 + n4);
      smem[(n4 + 0) * 65 + k] = v.x;
      smem[(n4 + 1) * 65 + k] = v.y;
      smem[(n4 + 2) * 65 + k] = v.z;
      smem[(n4 + 3) * 65 + k] = v.w;
    }
    __syncthreads();
#pragma unroll
    for (int it = 0; it < 2; it++) {
      int uidx = it * 256 + t;
      int nl = uidx >> 3;
      int j_half = (uidx >> 2) & 1;
      int pp_k = uidx & 3;
      int ng = mat * 64 + nl;                 // global n in [0,192)
      int n2 = ng >> 1;
      int sp = ((ng & 1) * 4 + pp_k) ^ (n2 & 7);
      int unit = n2 * 8 + sp;
      int j = kb * 2 + j_half;
      frag_u h, l;
#pragma unroll
      for (int e = 0; e < 8; e++) {
        float v = smem[nl * 65 + j_half * 32 + pp_k * 8 + e];
        bf16 hh = __float2bfloat16(v);
        h.e[e] = hh;
        l.e[e] = __float2bfloat16(v - __bfloat162float(hh));
      }
      size_t ob = (size_t)j * 6144 + unit * 8;
      *(bf16x8*)(void*)(Wt2_hi + ob) = h.v;
      *(bf16x8*)(void*)(Wt2_lo + ob) = l.v;
    }
  } else {                                    // ---- vsum-partial path ----
    const int v = bid - 48;                   // 0..255, rows [32v, 32v+32)
    float a0 = 0.f, a1 = 0.f, a2 = 0.f, a3 = 0.f;
    const float* xr = x + (size_t)v * 32 * EDIM + 4 * t;
    for (int i = 0; i < 32; i++) {            // full-row coalesced sweeps
      float4 xv = *(const float4*)(const void*)(xr + (size_t)i * EDIM);
      a0 += xv.x;
      a1 += xv.y;
      a2 += xv.z;
      a3 += xv.w;
    }
    float* rs = smem;                         // rowsum[1024]
    rs[4 * t + 0] = a0;
    rs[4 * t + 1] = a1;
    rs[4 * t + 2] = a2;
    rs[4 * t + 3] = a3;
    __syncthreads();
    const int col = t & 63;
    const int kq = t >> 6;                    // 0..3, k-range kq*256..+256
    float s = 0.f;
    const float* wvp = Wv + (size_t)(kq * 256) * 64 + col;
    const float* rsp = rs + kq * 256;
#pragma unroll 8
    for (int k8 = 0; k8 < 256; k8++) s += rsp[k8] * wvp[(size_t)k8 * 64];
    float* part = smem + 1024;                // [4][64]
    part[kq * 64 + col] = s;
    __syncthreads();
    if (t < 64)
      Vpart[(size_t)v * 64 + t] =
          part[t] + part[64 + t] + part[128 + t] + part[192 + t];
  }
}

// ---------------------------------------------------------------------------
// FUSED MAIN v13 — v10 gemm core + in-kernel attn via producer-chain spin.
// R7 confirmed: B-L2 traffic is roofline-bound (v12 doubled it: +6us, as
// modeled) -> keep v10's 32-row 1-block/CU shape (196 MB B-L2, minimum at
// full-grid). R6 confirmed work fuses fine but grid.sync costs 80us -> use
// an EARLIER-ONLY neighbor flag instead: attn for queries [32b-16,32b+16)
// needs K/V/Q rows [32b-20,32b+19] = blocks b-1 and b only. Deadlock-free:
// grid 256 <= 256 CUs (all blocks get a CU immediately); chain terminates
// at block 0. Cross-XCD: writer __threadfence + release-atomic flag;
// reader acquire-atomic spin (Guideline 16).
// Phases: [A] v10 A-panel DMA (1-KB row bursts, lane^(row&7) src swizzle)
//   + B reg ring-3 from packed Wt2 + vmcnt(18) + s_barrier; 16-round
//   barrier-free K-loop (18 MFMA/round/wave); kh-merge; epilogue writes
//   Q/K/V (+bias) to qkv (NO Vsum atomics). [B] fence + flag release.
//   [C] Vsum from Vpart (sum 128 partials/batch + S*bv; no cross-block dep)
//   overlapping [D] spin on flags[b-1]. [E] attn: 16 lanes/query float4,
//   5 window scores via shfl_xor(1,2,4,8), full-row softmax collapsed to
//   window exps + background (Vsum - window V) term.
// MFMA f32_16x16x32_bf16 split-bf16 (xh*wh + xh*wl + xl*wh):
//   A[m][k]: m=lane&15, k=(lane>>4)*8+e | B[k][n]: n=lane&15, k=(lane>>4)*8+e
//   D[m][n]: m=(lane>>4)*4+r, n=lane&15
// ---------------------------------------------------------------------------
__global__ __launch_bounds__(512, 2) void fused_main(
    const float* __restrict__ x, const bf16* __restrict__ Wt2_hi,
    const bf16* __restrict__ Wt2_lo, const float* __restrict__ bq,
    const float* __restrict__ bk, const float* __restrict__ bv,
    float* __restrict__ qkv, const float* __restrict__ Vpart,
    int* __restrict__ flags, float* __restrict__ out) {
  __shared__ __align__(16) char lds[131072];  // 32 rows x 4096 B (A panel)
  const int tid = threadIdx.x;
  const int lane = tid & 63;
  const int wave = tid >> 6;                  // 0..7
  const int nh = wave & 3;                    // n-group (3 n-tiles)
  const int kh = wave >> 2;                   // k-half
  const int quad = lane >> 4;
  const int l16 = lane & 15;
  const int rowBase = blockIdx.x * 32;        // identity map (neighbor chain)

  // B lane pointer (pre-swizzled pack layout): unit = nt*512 + loff bf16
  const int sp = ((l16 & 1) * 4 + quad) ^ ((l16 >> 1) & 7);
  const int loff = ((l16 >> 1) * 8 + sp) * 8;
  const bf16* bhp = Wt2_hi + (size_t)kh * 98304 + nh * 1536 + loff;
  const bf16* blp = Wt2_lo + (size_t)kh * 98304 + nh * 1536 + loff;

  bf16x8 Bh[3][3], Bl[3][3];
  f32x4 acc[2][3];
#pragma unroll
  for (int f = 0; f < 2; f++)
#pragma unroll
    for (int t = 0; t < 3; t++) acc[f][t] = (f32x4){0.f, 0.f, 0.f, 0.f};

#define LOADB(s, r)                                                          \
  {                                                                          \
    const bf16* _h = bhp + (size_t)(r) * 6144;                               \
    const bf16* _l = blp + (size_t)(r) * 6144;                               \
    Bh[s][0] = *(const bf16x8*)(const void*)(_h);                            \
    Bh[s][1] = *(const bf16x8*)(const void*)(_h + 512);                      \
    Bh[s][2] = *(const bf16x8*)(const void*)(_h + 1024);                     \
    Bl[s][0] = *(const bf16x8*)(const void*)(_l);                            \
    Bl[s][1] = *(const bf16x8*)(const void*)(_l + 512);                      \
    Bl[s][2] = *(const bf16x8*)(const void*)(_l + 1024);                     \
  }

  // ---- [A] stage A panel: wave w -> rows w*4..w*4+3, 4x 1-KB bursts/row
#pragma unroll
  for (int i = 0; i < 16; i++) {
    const int Rl = (wave << 2) | (i >> 2);
    const int g = i & 3;
    const char* src = (const char*)x + (size_t)(rowBase + Rl) * 4096 +
                      (size_t)g * 1024 + ((lane ^ (Rl & 7)) << 4);
    async_ld16(src, lds + Rl * 4096 + g * 1024);
  }
  asm volatile("" ::: "memory");              // DMAs strictly before B loads
  LOADB(0, 0);
  LOADB(1, 1);
  LOADB(2, 2);
  asm volatile("s_waitcnt vmcnt(18)" ::: "memory");  // own 16 DMAs retired
  __builtin_amdgcn_s_barrier();
  __builtin_amdgcn_sched_barrier(0);

  const char* aRow0 = lds + l16 * 4096;
  const char* aRow1 = lds + (16 + l16) * 4096;
  const int aE = (((quad * 2) ^ (l16 & 7)) << 4);

#pragma unroll
  for (int r = 0; r < 16; ++r) {
    const int Rk = kh * 16 + r;
    float4 a00 = *(const float4*)(const void*)(aRow0 + Rk * 128 + aE);
    float4 a01 = *(const float4*)(const void*)(aRow0 + Rk * 128 + (aE ^ 16));
    float4 a10 = *(const float4*)(const void*)(aRow1 + Rk * 128 + aE);
    float4 a11 = *(const float4*)(const void*)(aRow1 + Rk * 128 + (aE ^ 16));
    bf16x8 ah0, al0, ah1, al1;
    cvt_split(a00, a01, ah0, al0);
    cvt_split(a10, a11, ah1, al1);
    const int s = r % 3;
#pragma unroll
    for (int t = 0; t < 3; t++) {
      acc[0][t] =
          __builtin_amdgcn_mfma_f32_16x16x32_bf16(ah0, Bh[s][t], acc[0][t], 0, 0, 0);
      acc[0][t] =
          __builtin_amdgcn_mfma_f32_16x16x32_bf16(ah0, Bl[s][t], acc[0][t], 0, 0, 0);
      acc[0][t] =
          __builtin_amdgcn_mfma_f32_16x16x32_bf16(al0, Bh[s][t], acc[0][t], 0, 0, 0);
      acc[1][t] =
          __builtin_amdgcn_mfma_f32_16x16x32_bf16(ah1, Bh[s][t], acc[1][t], 0, 0, 0);
      acc[1][t] =
          __builtin_amdgcn_mfma_f32_16x16x32_bf16(ah1, Bl[s][t], acc[1][t], 0, 0, 0);
      acc[1][t] =
          __builtin_amdgcn_mfma_f32_16x16x32_bf16(al1, Bh[s][t], acc[1][t], 0, 0, 0);
    }
    if (r + 3 < 16) LOADB((r + 3) % 3, r + 3);
    asm volatile("" ::: "memory");
  }
#undef LOADB

  // kh-merge (reuse A-LDS; A fully consumed) — NO early returns.
  f32x4(*red)[64][6] = (f32x4(*)[64][6])lds;
  __syncthreads();
  if (kh == 1) {
#pragma unroll
    for (int f = 0; f < 2; f++)
#pragma unroll
      for (int t = 0; t < 3; t++) red[nh][lane][f * 3 + t] = acc[f][t];
  }
  __syncthreads();
  if (kh == 0) {
#pragma unroll
    for (int f = 0; f < 2; f++)
#pragma unroll
      for (int t = 0; t < 3; t++) acc[f][t] += red[nh][lane][f * 3 + t];
    // epilogue: bias + store Q/K/V (all to global qkv; Q needed by b+1)
#pragma unroll
    for (int f = 0; f < 2; f++)
#pragma unroll
      for (int t = 0; t < 3; t++) {
        int nt = nh * 3 + t;
        int n = nt * 16 + l16;
        int mat = n >> 6;
        int col = n & 63;
        float bias = (mat == 0) ? bq[col] : ((mat == 1) ? bk[col] : bv[col]);
        float* dst = qkv + (size_t)mat * MROWS * DDIM +
                     (size_t)(rowBase + f * 16 + quad * 4) * DDIM + col;
#pragma unroll
        for (int rr = 0; rr < 4; rr++) dst[rr * DDIM] = acc[f][t][rr] + bias;
      }
  }

  // ---- [B] release this block's rows to the chain
  __threadfence();                            // device-scope release of qkv
  __syncthreads();
  if (tid == 0)
    __hip_atomic_store(&flags[blockIdx.x], 1, __ATOMIC_RELEASE,
                       __HIP_MEMORY_SCOPE_AGENT);

  // ---- [C] Vsum from Vpart (no cross-block dep; overlaps neighbor's tail)
  float* vs_scr = (float*)lds;                // [2][4][64]
  {
    const int bb2 = tid >> 8;                 // batch 0/1
    const int rest = tid & 255;
    const int ch = rest >> 6;                 // 0..3
    const int col = rest & 63;
    float s = 0.f;
    const float* vp = Vpart + (size_t)(bb2 * 128 + ch * 32) * 64 + col;
#pragma unroll 4
    for (int p = 0; p < 32; p++) s += vp[(size_t)p * 64];
    vs_scr[(bb2 * 4 + ch) * 64 + col] = s;
  }
  __syncthreads();
  float* Vsum_l = (float*)(lds + 4096);       // [2][64]
  if (tid < 128) {
    const int bb2 = tid >> 6;
    const int col = tid & 63;
    Vsum_l[tid] = vs_scr[bb2 * 256 + col] + vs_scr[bb2 * 256 + 64 + col] +
                  vs_scr[bb2 * 256 + 128 + col] +
                  vs_scr[bb2 * 256 + 192 + col] + 4096.f * bv[col];
  }

  // ---- [D] wait for left neighbor's Q/K/V (earlier-only; deadlock-free)
  if (blockIdx.x > 0 && tid == 0) {
    while (__hip_atomic_load(&flags[blockIdx.x - 1], __ATOMIC_ACQUIRE,
                             __HIP_MEMORY_SCOPE_AGENT) == 0)
      __builtin_amdgcn_s_sleep(2);
  }
  __syncthreads();

  // ---- [E] attention for queries [qstart, qend)
  {
    const float* Kf = qkv + (size_t)MROWS * DDIM;
    const float* Vf = qkv + (size_t)2 * MROWS * DDIM;
    const int l16c = tid & 15;
    const int qloc = tid >> 4;                // 0..31
    const int qstart = (blockIdx.x == 0) ? 0 : rowBase - 16;
    const int qend = (blockIdx.x == 255) ? MROWS : rowBase + 16;
    for (int q0 = qstart; q0 < qend; q0 += 32) {
      const int qidx = q0 + qloc;
      const bool live = qidx < qend;
      const int qc = live ? qidx : (qend - 1); // clamp (dead groups harmless)
      const int bb2 = qc >> 12;
      const int i = qc & 4095;
      float4 q4 =
          *(const float4*)(const void*)(qkv + (size_t)qc * DDIM + 4 * l16c);
      float sc[5];
      float4 vv[5];
      bool val[5];
#pragma unroll
      for (int w = 0; w < 5; w++) {
        int j = i + 2 * w - 4;                // DIL*(w - WIN/2), DIL=2
        val[w] = (j >= 0) && (j < S_LEN);
        int jj = val[w] ? j : i;
        size_t off = (size_t)(bb2 * S_LEN + jj) * DDIM + 4 * l16c;
        float4 kk = *(const float4*)(const void*)(Kf + off);
        vv[w] = *(const float4*)(const void*)(Vf + off);
        float p = q4.x * kk.x + q4.y * kk.y + q4.z * kk.z + q4.w * kk.w;
        p += __shfl_xor(p, 1, 64);
        p += __shfl_xor(p, 2, 64);
        p += __shfl_xor(p, 4, 64);
        p += __shfl_xor(p, 8, 64);
        sc[w] = p;
      }
      float mx = 0.f;                         // background score 0 in the max
#pragma unroll
      for (int w = 0; w < 5; w++)
        if (val[w]) mx = fmaxf(mx, sc[w]);
      float denom = 0.f;
      float4 accv = {0.f, 0.f, 0.f, 0.f}, vsel = {0.f, 0.f, 0.f, 0.f};
      int nval = 0;
#pragma unroll
      for (int w = 0; w < 5; w++)
        if (val[w]) {
          float pexp = __expf(sc[w] - mx);
          denom += pexp;
          accv.x += pexp * vv[w].x;
          accv.y += pexp * vv[w].y;
          accv.z += pexp * vv[w].z;
          accv.w += pexp * vv[w].w;
          vsel.x += vv[w].x;
          vsel.y += vv[w].y;
          vsel.z += vv[w].z;
          vsel.w += vv[w].w;
          nval++;
        }
      float pbg = __expf(-mx);
      denom += pbg * (float)(S_LEN - nval);
      float4 vsm =
          *(const float4*)(const void*)(Vsum_l + bb2 * 64 + 4 * l16c);
      accv.x += pbg * (vsm.x - vsel.x);
      accv.y += pbg * (vsm.y - vsel.y);
      accv.z += pbg * (vsm.z - vsel.z);
      accv.w += pbg * (vsm.w - vsel.w);
      float4 o = {accv.x / denom, accv.y / denom, accv.z / denom,
                  accv.w / denom};
      if (live)
        *(float4*)(void*)(out + (size_t)qidx * DDIM + 4 * l16c) = o;
    }
  }
}

// ---------------------------------------------------------------------------
extern "C" void kernel_launch(void* const* d_in, const int* in_sizes, int n_in,
                              void* d_out, int out_size, void* d_ws,
                              size_t ws_size, hipStream_t stream) {
  const float* x = (const float*)d_in[0];
  const float* Wq = (const float*)d_in[1];
  const float* bq = (const float*)d_in[2];
  const float* Wk = (const float*)d_in[3];
  const float* bk = (const float*)d_in[4];
  const float* Wv = (const float*)d_in[5];
  const float* bv = (const float*)d_in[6];
  float* out = (float*)d_out;

  char* ws = (char*)d_ws;
  bf16* Wt2_hi = (bf16*)ws;                   // 393216 B
  bf16* Wt2_lo = (bf16*)(ws + 393216);        // 393216 B
  float* qkv = (float*)(ws + 786432);         // 6291456 B
  float* Vpart = (float*)(ws + 7077888);      // 256*64*4 = 65536 B
  int* flags = (int*)(ws + 7143424);          // 1024 B  (total ~6.82 MiB)

  hipLaunchKernelGGL(prep_kernel, dim3(304), dim3(256), 0, stream, x, Wq, Wk,
                     Wv, Wt2_hi, Wt2_lo, Vpart, flags);
  hipLaunchKernelGGL(fused_main, dim3(256), dim3(512), 0, stream, x, Wt2_hi,
                     Wt2_lo, bq, bk, bv, qkv, Vpart, flags, out);
}

// Round 10
// 105.499 us; speedup vs baseline: 1.4504x; 1.4504x over previous
//
#include <hip/hip_runtime.h>
#include <hip/hip_bf16.h>

typedef __hip_bfloat16 bf16;
typedef short bf16x8 __attribute__((ext_vector_type(8)));
typedef float f32x4 __attribute__((ext_vector_type(4)));

#define S_LEN 4096
#define NBATCH 2
#define EDIM 1024
#define DDIM 64
#define MROWS (NBATCH * S_LEN)   // 8192

#define GLOBAL_AS __attribute__((address_space(1)))
#define LDS_AS __attribute__((address_space(3)))

union frag_u { bf16x8 v; bf16 e[8]; };

// async 16B global -> LDS (dest wave-uniform; HW adds lane*16; src per-lane)
__device__ __forceinline__ void async_ld16(const void* gp, void* lp) {
  __builtin_amdgcn_global_load_lds((const GLOBAL_AS void*)gp,
                                   (LDS_AS void*)lp, 16, 0, 0);
}

// f32x8 -> split bf16 hi/lo fragments (x ~= hi + lo, rel err ~2^-17)
__device__ __forceinline__ void cvt_split(const float4& a, const float4& b,
                                          bf16x8& hi, bf16x8& lo) {
  float v[8] = {a.x, a.y, a.z, a.w, b.x, b.y, b.z, b.w};
  frag_u h, l;
#pragma unroll
  for (int e = 0; e < 8; e++) {
    bf16 hh = __float2bfloat16(v[e]);
    h.e[e] = hh;
    l.e[e] = __float2bfloat16(v[e] - __bfloat162float(hh));
  }
  hi = h.v;
  lo = l.v;
}

// ---------------------------------------------------------------------------
// Pack weights (f32, k-major [1024][64]) -> split-bf16 in ROUND-MAJOR
// order: Wt2[j=0..31][unit u=0..767][8 bf16], round j covers k in
// [j*32, j*32+32). Unit for (n, kk): n2 = n>>1, pp = (n&1)*4 + (kk>>3),
// sp = pp ^ (n2 & 7), u = n2*8 + sp, elem = kk&7. A round block = 12288 B.
// The gemm reads lane units DIRECTLY from global (each (nt, round) is a
// contiguous, fully-consumed 1 KB segment -> perfect coalescing, L2-hot).
// Grid 48 = 3 mats x 16 k-blocks. Block 0 zeroes Vsum.
// ---------------------------------------------------------------------------
__global__ __launch_bounds__(256) void pack_w_kernel(
    const float* __restrict__ Wq, const float* __restrict__ Wk,
    const float* __restrict__ Wv, bf16* __restrict__ Wt2_hi,
    bf16* __restrict__ Wt2_lo, float* __restrict__ Vsum) {
  __shared__ float tile[64 * 65];
  const int mat = blockIdx.x >> 4;
  const int kb = blockIdx.x & 15;             // 64-k block -> rounds 2kb,2kb+1
  const int t = threadIdx.x;
  if (blockIdx.x == 0 && t < NBATCH * DDIM) Vsum[t] = 0.f;
  const float* W = (mat == 0) ? Wq : ((mat == 1) ? Wk : Wv);

#pragma unroll
  for (int i = 0; i < 4; i++) {
    int F = (i * 256 + t) * 4;                // flat f32 idx in [0,4096)
    int k = F >> 6;
    int n4 = F & 63;
    float4 v = *(const float4*)(const void*)(W + (size_t)(kb * 64 + k) * 64 + n4);
    tile[(n4 + 0) * 65 + k] = v.x;
    tile[(n4 + 1) * 65 + k] = v.y;
    tile[(n4 + 2) * 65 + k] = v.z;
    tile[(n4 + 3) * 65 + k] = v.w;
  }
  __syncthreads();

  // 512 units (hi+lo written together): nl, j_half, pp_k
#pragma unroll
  for (int it = 0; it < 2; it++) {
    int uidx = it * 256 + t;
    int nl = uidx >> 3;
    int j_half = (uidx >> 2) & 1;
    int pp_k = uidx & 3;
    int ng = mat * 64 + nl;                   // global n in [0,192)
    int n2 = ng >> 1;
    int sp = ((ng & 1) * 4 + pp_k) ^ (n2 & 7);
    int unit = n2 * 8 + sp;
    int j = kb * 2 + j_half;
    frag_u h, l;
#pragma unroll
    for (int e = 0; e < 8; e++) {
      float v = tile[nl * 65 + j_half * 32 + pp_k * 8 + e];
      bf16 hh = __float2bfloat16(v);
      h.e[e] = hh;
      l.e[e] = __float2bfloat16(v - __bfloat162float(hh));
    }
    size_t ob = (size_t)j * 6144 + unit * 8;
    *(bf16x8*)(void*)(Wt2_hi + ob) = h.v;
    *(bf16x8*)(void*)(Wt2_lo + ob) = l.v;
  }
}

// ---------------------------------------------------------------------------
// Fused QKV GEMM v14 — v10 + TWO-STAGE A-PANEL PROLOGUE.
// (Resubmission of R9 — lost to an infra failure, no kernel change.)
// v10's remaining structure flaw: all 8 waves wait for the ENTIRE 128 KB
// A-panel before round 0, though rounds 0-7 read only bursts g{0,2}
// (kh=0: row bytes [0,1K); kh=1: [2K,3K)). v14 stages 64 KB (g0,g2) ->
// vmcnt(18)+barrier -> compute rounds 0-7 while g{1,3} stream in
// progressively (2 DMAs at the END of rounds 0..3, issued AFTER that
// round's B-issue so B(r) waits keep >=3-round slack and in-order
// retirement drains the DMAs early) -> vmcnt(18)+barrier before round 8
// (outstanding = B(8,9,10) = 18 loads, all younger than phase-2 DMAs).
// Everything else identical to v10: B reg ring-3 from packed Wt2 (L2-hot,
// issue at round end), swizzled ds_read_b128 A-frags (2-way = free),
// 18 MFMA/round/wave, kh-merge via LDS, epilogue bias+store+Vsum atomics.
// Shape: 8 waves = nh(0..3) x kh(0..1), 32 rows/block, grid 256 (1 blk/CU).
// MFMA f32_16x16x32_bf16 split-bf16 (xh*wh + xh*wl + xl*wh):
//   A[m][k]: m=lane&15, k=(lane>>4)*8+e | B[k][n]: n=lane&15, k=(lane>>4)*8+e
//   D[m][n]: m=(lane>>4)*4+r, n=lane&15
// ---------------------------------------------------------------------------
__global__ __launch_bounds__(512, 2) void qkv_gemm_kernel(
    const float* __restrict__ x, const bf16* __restrict__ Wt2_hi,
    const bf16* __restrict__ Wt2_lo, const float* __restrict__ bq,
    const float* __restrict__ bk, const float* __restrict__ bv,
    float* __restrict__ qkv, float* __restrict__ Vsum) {
  __shared__ __align__(16) char lds[131072];  // 32 rows x 4096 B (A panel)
  const int tid = threadIdx.x;
  const int lane = tid & 63;
  const int wave = tid >> 6;                  // 0..7
  const int nh = wave & 3;                    // n-group (3 n-tiles)
  const int kh = wave >> 2;                   // k-half
  const int quad = lane >> 4;
  const int l16 = lane & 15;
  const int rowBase = blockIdx.x * 32;

  // B lane pointer (pre-swizzled pack layout): unit = nt*512 + loff bf16
  const int sp = ((l16 & 1) * 4 + quad) ^ ((l16 >> 1) & 7);
  const int loff = ((l16 >> 1) * 8 + sp) * 8;
  const bf16* bhp = Wt2_hi + (size_t)kh * 98304 + nh * 1536 + loff;  // 16*6144
  const bf16* blp = Wt2_lo + (size_t)kh * 98304 + nh * 1536 + loff;

  bf16x8 Bh[3][3], Bl[3][3];                  // [slot][t]
  f32x4 acc[2][3];
#pragma unroll
  for (int f = 0; f < 2; f++)
#pragma unroll
    for (int t = 0; t < 3; t++) acc[f][t] = (f32x4){0.f, 0.f, 0.f, 0.f};

#define LOADB(s, r)                                                          \
  {                                                                          \
    const bf16* _h = bhp + (size_t)(r) * 6144;                               \
    const bf16* _l = blp + (size_t)(r) * 6144;                               \
    Bh[s][0] = *(const bf16x8*)(const void*)(_h);                            \
    Bh[s][1] = *(const bf16x8*)(const void*)(_h + 512);                      \
    Bh[s][2] = *(const bf16x8*)(const void*)(_h + 1024);                     \
    Bl[s][0] = *(const bf16x8*)(const void*)(_l);                            \
    Bl[s][1] = *(const bf16x8*)(const void*)(_l + 512);                      \
    Bl[s][2] = *(const bf16x8*)(const void*)(_l + 1024);                     \
  }
  // A-DMA helper: wave's row Rl, burst g (1-KB contiguous, lane^(Rl&7)
  // source swizzle = LDS image LDS[R][c] = x[R][c ^ (R&7)])
#define ADMA(Rl, g)                                                          \
  async_ld16((const char*)x + (size_t)(rowBase + (Rl)) * 4096 +              \
                 (size_t)(g) * 1024 + ((lane ^ ((Rl) & 7)) << 4),            \
             lds + (Rl) * 4096 + (g) * 1024)

  // ---- phase-1 staging: bursts g in {0,2} of own 4 rows (8 DMAs) ----
#pragma unroll
  for (int i = 0; i < 8; i++) ADMA((wave << 2) | (i >> 1), (i & 1) * 2);
  asm volatile("" ::: "memory");              // DMAs strictly before B loads
  LOADB(0, 0);
  LOADB(1, 1);
  LOADB(2, 2);
  // own 8 phase-1 DMAs retired (18 B loads may remain), then cross-wave
  asm volatile("s_waitcnt vmcnt(18)" ::: "memory");
  __builtin_amdgcn_s_barrier();
  __builtin_amdgcn_sched_barrier(0);

  // A fragment bases: rows l16 and 16+l16 ((16+l16)&7 == l16&7)
  const char* aRow0 = lds + l16 * 4096;
  const char* aRow1 = lds + (16 + l16) * 4096;
  const int aE = (((quad * 2) ^ (l16 & 7)) << 4);

#define COMPUTE(r)                                                           \
  {                                                                          \
    const int Rk = kh * 16 + (r);                                            \
    float4 a00 = *(const float4*)(const void*)(aRow0 + Rk * 128 + aE);       \
    float4 a01 = *(const float4*)(const void*)(aRow0 + Rk * 128 + (aE ^ 16));\
    float4 a10 = *(const float4*)(const void*)(aRow1 + Rk * 128 + aE);       \
    float4 a11 = *(const float4*)(const void*)(aRow1 + Rk * 128 + (aE ^ 16));\
    bf16x8 ah0, al0, ah1, al1;                                               \
    cvt_split(a00, a01, ah0, al0);                                           \
    cvt_split(a10, a11, ah1, al1);                                           \
    const int s = (r) % 3;                                                   \
    _Pragma("unroll") for (int t = 0; t < 3; t++) {                          \
      acc[0][t] = __builtin_amdgcn_mfma_f32_16x16x32_bf16(ah0, Bh[s][t],     \
                                                          acc[0][t], 0, 0, 0);\
      acc[0][t] = __builtin_amdgcn_mfma_f32_16x16x32_bf16(ah0, Bl[s][t],     \
                                                          acc[0][t], 0, 0, 0);\
      acc[0][t] = __builtin_amdgcn_mfma_f32_16x16x32_bf16(al0, Bh[s][t],     \
                                                          acc[0][t], 0, 0, 0);\
      acc[1][t] = __builtin_amdgcn_mfma_f32_16x16x32_bf16(ah1, Bh[s][t],     \
                                                          acc[1][t], 0, 0, 0);\
      acc[1][t] = __builtin_amdgcn_mfma_f32_16x16x32_bf16(ah1, Bl[s][t],     \
                                                          acc[1][t], 0, 0, 0);\
      acc[1][t] = __builtin_amdgcn_mfma_f32_16x16x32_bf16(al1, Bh[s][t],     \
                                                          acc[1][t], 0, 0, 0);\
    }                                                                        \
  }

  // ---- rounds 0-7 (consume g0/g2); phase-2 DMAs (g1,g3) drip in r=0..3
#pragma unroll
  for (int r = 0; r < 8; ++r) {
    COMPUTE(r);
    LOADB((r + 3) % 3, r + 3);                // B issue at round end
    if (r < 4) {                              // after B-issue: keeps B slack
      ADMA((wave << 2) | r, 1);
      ADMA((wave << 2) | r, 3);
    }
    asm volatile("" ::: "memory");            // pin issue positions
  }
  // before round 8: outstanding = B(8),B(9),B(10) = 18 loads, all younger
  // than the phase-2 DMAs -> vmcnt(18) certifies own DMAs; barrier: all.
  asm volatile("s_waitcnt vmcnt(18)" ::: "memory");
  __builtin_amdgcn_s_barrier();
  __builtin_amdgcn_sched_barrier(0);

  // ---- rounds 8-15 (consume g1/g3)
#pragma unroll
  for (int r = 8; r < 16; ++r) {
    COMPUTE(r);
    if (r + 3 < 16) LOADB((r + 3) % 3, r + 3);
    asm volatile("" ::: "memory");
  }
#undef COMPUTE
#undef ADMA
#undef LOADB

  // merge k-halves (reuse A-LDS; A fully consumed): kh=1 export, kh=0 absorb
  f32x4(*red)[64][6] = (f32x4(*)[64][6])lds;   // 24.5 KB < 128 KB
  __syncthreads();                             // all waves done reading A
  if (kh == 1) {
#pragma unroll
    for (int f = 0; f < 2; f++)
#pragma unroll
      for (int t = 0; t < 3; t++) red[nh][lane][f * 3 + t] = acc[f][t];
  }
  __syncthreads();
  if (kh == 1) return;
#pragma unroll
  for (int f = 0; f < 2; f++)
#pragma unroll
    for (int t = 0; t < 3; t++) acc[f][t] += red[nh][lane][f * 3 + t];

  // epilogue: bias + store + V column sums
  const int bb = rowBase >> 12;
#pragma unroll
  for (int f = 0; f < 2; f++)
#pragma unroll
    for (int t = 0; t < 3; t++) {
      int nt = nh * 3 + t;
      int n = nt * 16 + l16;
      int mat = n >> 6;
      int col = n & 63;
      float bias = (mat == 0) ? bq[col] : ((mat == 1) ? bk[col] : bv[col]);
      float* dst = qkv + (size_t)mat * MROWS * DDIM +
                   (size_t)(rowBase + f * 16 + quad * 4) * DDIM + col;
      float vs = 0.f;
#pragma unroll
      for (int rr = 0; rr < 4; rr++) {
        float val = acc[f][t][rr] + bias;
        dst[rr * DDIM] = val;
        vs += val;
      }
      if (nt >= 8) {                          // V tiles -> Vsum
        vs += __shfl_xor(vs, 16, 64);
        vs += __shfl_xor(vs, 32, 64);
        if (quad == 0) atomicAdd(&Vsum[bb * DDIM + (n - 128)], vs);
      }
    }
}

// ---------------------------------------------------------------------------
// Attention v14: 16 lanes/query (float4/lane), 16 q/block, grid 512 x 256.
// Full-row softmax collapses to: 5 window exps + (S - nvalid) background
// exp(0-m) terms; background numerator = Vsum - sum(window V).
// (float4/16-lane variant verified bit-compatible in R6/R8 fused phases.)
// ---------------------------------------------------------------------------
__global__ __launch_bounds__(256) void attn_kernel(
    const float* __restrict__ qkv, const float* __restrict__ Vsum,
    float* __restrict__ out) {
  const float* Qf = qkv;
  const float* Kf = qkv + (size_t)MROWS * DDIM;
  const float* Vf = qkv + (size_t)2 * MROWS * DDIM;
  const int l16c = threadIdx.x & 15;
  const int qidx = blockIdx.x * 16 + (threadIdx.x >> 4);
  const int b = qidx >> 12;
  const int i = qidx & 4095;

  float4 q = *(const float4*)(const void*)(Qf + (size_t)qidx * DDIM + 4 * l16c);
  float sc[5];
  float4 vv[5];
  bool val[5];
#pragma unroll
  for (int w = 0; w < 5; w++) {
    int j = i + 2 * w - 4;                    // DIL*(w - WIN/2), DIL=2
    val[w] = (j >= 0) && (j < S_LEN);
    int jj = val[w] ? j : i;
    size_t off = (size_t)(b * S_LEN + jj) * DDIM + 4 * l16c;
    float4 kk = *(const float4*)(const void*)(Kf + off);
    vv[w] = *(const float4*)(const void*)(Vf + off);
    float p = q.x * kk.x + q.y * kk.y + q.z * kk.z + q.w * kk.w;
    p += __shfl_xor(p, 1, 64);
    p += __shfl_xor(p, 2, 64);
    p += __shfl_xor(p, 4, 64);
    p += __shfl_xor(p, 8, 64);
    sc[w] = p;
  }

  float mx = 0.f;                             // background score 0 in the max
#pragma unroll
  for (int w = 0; w < 5; w++)
    if (val[w]) mx = fmaxf(mx, sc[w]);

  float denom = 0.f;
  float4 accv = {0.f, 0.f, 0.f, 0.f}, vsel = {0.f, 0.f, 0.f, 0.f};
  int nval = 0;
#pragma unroll
  for (int w = 0; w < 5; w++)
    if (val[w]) {
      float pexp = __expf(sc[w] - mx);
      denom += pexp;
      accv.x += pexp * vv[w].x;
      accv.y += pexp * vv[w].y;
      accv.z += pexp * vv[w].z;
      accv.w += pexp * vv[w].w;
      vsel.x += vv[w].x;
      vsel.y += vv[w].y;
      vsel.z += vv[w].z;
      vsel.w += vv[w].w;
      nval++;
    }
  float pbg = __expf(-mx);
  denom += pbg * (float)(S_LEN - nval);
  float4 vsm = *(const float4*)(const void*)(Vsum + b * DDIM + 4 * l16c);
  accv.x += pbg * (vsm.x - vsel.x);
  accv.y += pbg * (vsm.y - vsel.y);
  accv.z += pbg * (vsm.z - vsel.z);
  accv.w += pbg * (vsm.w - vsel.w);

  float4 o = {accv.x / denom, accv.y / denom, accv.z / denom, accv.w / denom};
  *(float4*)(void*)(out + (size_t)qidx * DDIM + 4 * l16c) = o;
}

// ---------------------------------------------------------------------------
extern "C" void kernel_launch(void* const* d_in, const int* in_sizes, int n_in,
                              void* d_out, int out_size, void* d_ws,
                              size_t ws_size, hipStream_t stream) {
  const float* x = (const float*)d_in[0];
  const float* Wq = (const float*)d_in[1];
  const float* bq = (const float*)d_in[2];
  const float* Wk = (const float*)d_in[3];
  const float* bk = (const float*)d_in[4];
  const float* Wv = (const float*)d_in[5];
  const float* bv = (const float*)d_in[6];
  float* out = (float*)d_out;

  char* ws = (char*)d_ws;
  bf16* Wt2_hi = (bf16*)ws;                   // 32*6144*2 = 393216 B
  bf16* Wt2_lo = (bf16*)(ws + 393216);        // 393216 B
  float* qkv = (float*)(ws + 786432);         // 3*8192*64*4 = 6291456 B
  float* Vsum = (float*)(ws + 786432 + 6291456);  // 512 B
  // total workspace ~7.1 MB

  hipLaunchKernelGGL(pack_w_kernel, dim3(48), dim3(256), 0, stream, Wq, Wk, Wv,
                     Wt2_hi, Wt2_lo, Vsum);
  hipLaunchKernelGGL(qkv_gemm_kernel, dim3(256), dim3(512), 0, stream, x,
                     Wt2_hi, Wt2_lo, bq, bk, bv, qkv, Vsum);
  hipLaunchKernelGGL(attn_kernel, dim3(512), dim3(256), 0, stream, qkv, Vsum,
                     out);
}